// Round 1
// baseline (5774.296 us; speedup 1.0000x reference)
//
#include <hip/hip_runtime.h>
#include <cfloat>

// Problem constants (match reference setup_inputs)
constexpr int NB = 8, NN = 3000, NM = 3000, KK = 8;
constexpr int CAP = 48;                       // per-row/col sparse capacity: 8 base + up to 40 extras
constexpr int SUBS = 8, COLS = 64;            // column-topk tiling
constexpr int RPS = NN / SUBS;                // rows per sub-chunk = 375
constexpr float SCALE   = 14.426950408889634f;   // 1/(EPS*ln2), EPS=0.1
constexpr float UNSCALE = 0.06931471805599453f;  // EPS*ln2
constexpr float THRESH  = 0.1f;

#if __has_builtin(__builtin_amdgcn_exp2f)
#define FEXP2(x) __builtin_amdgcn_exp2f(x)
#else
#define FEXP2(x) exp2f(x)
#endif
#if __has_builtin(__builtin_amdgcn_logf)
#define FLOG2(x) __builtin_amdgcn_logf(x)   // v_log_f32 = log2
#else
#define FLOG2(x) __log2f(x)
#endif

// ---------------------------------------------------------------------------
// K1: per-(b,n) row: L2 norm + top-8 smallest (indices). Row staged in LDS.
// Ordering on raw C == ordering on normalized C (positive per-row scale).
// ---------------------------------------------------------------------------
__global__ __launch_bounds__(256) void k_rowprep(const float* __restrict__ C,
                                                 float* __restrict__ norms,
                                                 int* __restrict__ rowsel) {
  int bn = blockIdx.x;                       // b*NN + n
  const float* row = C + (size_t)bn * NM;
  __shared__ __align__(16) float lds[NM];
  __shared__ float rv[4];
  __shared__ int   ri[4];
  int tid = threadIdx.x;
  float sq = 0.f;
  for (int i = tid; i < NM / 4; i += 256) {
    float4 f = reinterpret_cast<const float4*>(row)[i];
    reinterpret_cast<float4*>(lds)[i] = f;
    sq += f.x * f.x + f.y * f.y + f.z * f.z + f.w * f.w;
  }
#pragma unroll
  for (int o = 32; o; o >>= 1) sq += __shfl_down(sq, o);
  int wid = tid >> 6, lane = tid & 63;
  if (lane == 0) rv[wid] = sq;
  __syncthreads();
  if (tid == 0) norms[bn] = sqrtf(rv[0] + rv[1] + rv[2] + rv[3]);
  __syncthreads();  // rv reused below

  for (int p = 0; p < KK; ++p) {
    float mv = FLT_MAX; int mi = NM;
    for (int i = tid; i < NM; i += 256) {
      float v = lds[i];
      if (v < mv) { mv = v; mi = i; }        // strided asc indices -> stable
    }
#pragma unroll
    for (int o = 32; o; o >>= 1) {
      float ov = __shfl_down(mv, o); int oi = __shfl_down(mi, o);
      if (ov < mv || (ov == mv && oi < mi)) { mv = ov; mi = oi; }
    }
    if (lane == 0) { rv[wid] = mv; ri[wid] = mi; }
    __syncthreads();
    if (tid == 0) {
      float bv = rv[0]; int bi = ri[0];
#pragma unroll
      for (int w = 1; w < 4; ++w)
        if (rv[w] < bv || (rv[w] == bv && ri[w] < bi)) { bv = rv[w]; bi = ri[w]; }
      rowsel[(size_t)bn * KK + p] = bi;
      lds[bi] = FLT_MAX;                     // exclude for next pass
    }
    __syncthreads();
  }
}

// ---------------------------------------------------------------------------
// K2: per-(b,m) column: top-8 largest of C/norm. Block = 64 cols x 8 row-chunks.
// Per-thread register top-8 (stable, strict >), then LDS merge with
// (val desc, idx asc) comparator  == lax.top_k tie semantics.
// ---------------------------------------------------------------------------
__global__ __launch_bounds__(512) void k_coltop(const float* __restrict__ C,
                                                const float* __restrict__ norms,
                                                int* __restrict__ colsel) {
  int b = blockIdx.y;
  int cg = blockIdx.x;
  int tid = threadIdx.x;
  int col = tid & (COLS - 1);
  int sub = tid >> 6;                         // 0..7
  int m = cg * COLS + col;
  __shared__ float inv[NN];
  __shared__ float sv[SUBS * COLS * 8];
  __shared__ int   si[SUBS * COLS * 8];
  for (int r = tid; r < NN; r += 512)
    inv[r] = 1.0f / fmaxf(norms[(size_t)b * NN + r], 1e-12f);
  __syncthreads();

  float tv[8]; int ti[8];
#pragma unroll
  for (int q = 0; q < 8; ++q) { tv[q] = -FLT_MAX; ti[q] = 0x7fffffff; }

  if (m < NM) {
    const float* base = C + ((size_t)b * NN + (size_t)sub * RPS) * NM + m;
    for (int r = 0; r < RPS; r += 5) {        // 375 = 5*75
#pragma unroll
      for (int j = 0; j < 5; ++j) {
        int rr = r + j;
        float val = base[(size_t)rr * NM] * inv[sub * RPS + rr];
        if (val > tv[7]) {                    // stable insert (ties keep earlier n)
          int idx = sub * RPS + rr;
          int pos = 8;
#pragma unroll
          for (int q = 7; q >= 0; --q) if (val > tv[q]) pos = q;
#pragma unroll
          for (int q = 7; q >= 1; --q) if (q > pos) { tv[q] = tv[q-1]; ti[q] = ti[q-1]; }
#pragma unroll
          for (int q = 0; q < 8; ++q) if (q == pos) { tv[q] = val; ti[q] = idx; }
        }
      }
    }
  }
#pragma unroll
  for (int q = 0; q < 8; ++q) { sv[tid * 8 + q] = tv[q]; si[tid * 8 + q] = ti[q]; }
  __syncthreads();

  if (tid < COLS) {
    int mcol = cg * COLS + tid;
    if (mcol < NM) {
      unsigned long long used = 0;
      for (int p = 0; p < KK; ++p) {
        float bv = -FLT_MAX; int bi = 0x7fffffff; int bq = 0;
        for (int c = 0; c < SUBS; ++c) {
#pragma unroll
          for (int q = 0; q < 8; ++q) {
            int bit = c * 8 + q;
            if ((used >> bit) & 1ull) continue;
            float v = sv[(c * COLS + tid) * 8 + q];
            int   n = si[(c * COLS + tid) * 8 + q];
            if (v > bv || (v == bv && n < bi)) { bv = v; bi = n; bq = bit; }
          }
        }
        used |= 1ull << bq;
        colsel[((size_t)b * NM + mcol) * KK + p] = bi;
      }
    }
  }
}

// ---------------------------------------------------------------------------
// K3: fill base slots (0..7) of CSR (rows) and CSC (cols).
// Values stored pre-scaled: val2 = (C/norm) / (EPS*ln2), packed (idx, val).
// ---------------------------------------------------------------------------
__global__ __launch_bounds__(256) void k_fillbase(const float* __restrict__ C,
    const float* __restrict__ norms, const int* __restrict__ rowsel,
    const int* __restrict__ colsel, int2* __restrict__ r_pk, int2* __restrict__ c_pk) {
  int t = blockIdx.x * 256 + threadIdx.x;
  if (t >= NB * NN * KK) return;
  int k = t % KK; int bn = t / KK;
  int b = bn / NN; int n = bn % NN;
  {
    int m = rowsel[t];
    float iv = 1.0f / fmaxf(norms[bn], 1e-12f);
    float v2 = C[((size_t)b * NN + n) * NM + m] * iv * SCALE;
    r_pk[(size_t)bn * CAP + k] = make_int2(m, __float_as_int(v2));
  }
  {
    int m2 = bn % NM;                         // reinterpret bn as b*NM+m
    int n2 = colsel[t];
    float iv = 1.0f / fmaxf(norms[(size_t)b * NN + n2], 1e-12f);
    float v2 = C[((size_t)b * NN + n2) * NM + m2] * iv * SCALE;
    c_pk[(size_t)bn * CAP + k] = make_int2(n2, __float_as_int(v2));
  }
  (void)k;
}

// ---------------------------------------------------------------------------
// K4: append non-duplicate extras. dup(n,m) := m in rowsel[n] AND n in colsel[m]
// (already present in the other list's base slots).
// ---------------------------------------------------------------------------
__global__ __launch_bounds__(256) void k_fillextra(const float* __restrict__ C,
    const float* __restrict__ norms, const int* __restrict__ rowsel,
    const int* __restrict__ colsel, int* r_cnt, int* c_cnt,
    int2* __restrict__ r_pk, int2* __restrict__ c_pk) {
  int t = blockIdx.x * 256 + threadIdx.x;
  if (t >= NB * NM * KK) return;
  int bm = t / KK;
  int b = bm / NM; int m = bm % NM;
  {  // colsel entry (b,m,k): row n gains column m unless duplicate
    int n = colsel[t];
    const int* rs = rowsel + ((size_t)b * NN + n) * KK;
    bool dup = false;
#pragma unroll
    for (int q = 0; q < KK; ++q) dup |= (rs[q] == m);
    if (!dup) {
      int slot = 8 + atomicAdd(&r_cnt[(size_t)b * NN + n], 1);
      if (slot < CAP) {
        float iv = 1.0f / fmaxf(norms[(size_t)b * NN + n], 1e-12f);
        float v2 = C[((size_t)b * NN + n) * NM + m] * iv * SCALE;
        r_pk[((size_t)b * NN + n) * CAP + slot] = make_int2(m, __float_as_int(v2));
      }
    }
  }
  {  // rowsel entry (b,n2,k): column mm gains row n2 unless duplicate
    int n2 = m;
    int mm = rowsel[t];
    const int* cs = colsel + ((size_t)b * NM + mm) * KK;
    bool dup = false;
#pragma unroll
    for (int q = 0; q < KK; ++q) dup |= (cs[q] == n2);
    if (!dup) {
      int slot = 8 + atomicAdd(&c_cnt[(size_t)b * NM + mm], 1);
      if (slot < CAP) {
        float iv = 1.0f / fmaxf(norms[(size_t)b * NN + n2], 1e-12f);
        float v2 = C[((size_t)b * NN + n2) * NM + mm] * iv * SCALE;
        c_pk[((size_t)b * NM + mm) * CAP + slot] = make_int2(n2, __float_as_int(v2));
      }
    }
  }
}

// ---------------------------------------------------------------------------
// K5: sparse log-domain Sinkhorn, one block per batch. Base-2 potentials:
// U = u/(EPS*ln2). Update: U <- log2(mu+1e-8) - log2(1e-8+s) + U, where
// s = sum 2^(U+V-val2) equals the reference's natural-domain row sum.
// Early stop: sum|dU| * EPS*ln2 < 0.1 (converging iteration commits, matches
// the reference's done-freeze semantics).
// ---------------------------------------------------------------------------
__global__ __launch_bounds__(1024) void k_sinkhorn(const float* __restrict__ mu,
    const float* __restrict__ nu, const int2* __restrict__ r_pk,
    const int* __restrict__ r_cnt, const int2* __restrict__ c_pk,
    const int* __restrict__ c_cnt, float* __restrict__ cost) {
  int b = blockIdx.x, tid = threadIdx.x;
  __shared__ float U[NN], V[NM], LMU[NN], LNU[NM];
  __shared__ float red[16];
  __shared__ int s_stop;
  for (int i = tid; i < NN; i += 1024) { U[i] = 0.f; LMU[i] = FLOG2(mu[(size_t)b*NN+i] + 1e-8f); }
  for (int i = tid; i < NM; i += 1024) { V[i] = 0.f; LNU[i] = FLOG2(nu[(size_t)b*NM+i] + 1e-8f); }
  __syncthreads();
  int wid = tid >> 6, lane = tid & 63;

  for (int it = 0; it < 100; ++it) {
    float errsum = 0.f;
    for (int n = tid; n < NN; n += 1024) {
      int cnt = 8 + min(r_cnt[(size_t)b*NN + n], CAP - 8);
      const int2* p = r_pk + ((size_t)b*NN + n) * CAP;
      float u = U[n], s = 0.f;
      for (int e = 0; e < cnt; ++e) {
        int2 pk = p[e];
        s += FEXP2(u + V[pk.x] - __int_as_float(pk.y));
      }
      float un = LMU[n] - FLOG2(1e-8f + s) + u;
      errsum += fabsf(un - u);
      U[n] = un;
    }
    __syncthreads();
    for (int m = tid; m < NM; m += 1024) {
      int cnt = 8 + min(c_cnt[(size_t)b*NM + m], CAP - 8);
      const int2* p = c_pk + ((size_t)b*NM + m) * CAP;
      float v = V[m], s = 0.f;
      for (int e = 0; e < cnt; ++e) {
        int2 pk = p[e];
        s += FEXP2(U[pk.x] + v - __int_as_float(pk.y));
      }
      V[m] = LNU[m] - FLOG2(1e-8f + s) + v;
    }
#pragma unroll
    for (int o = 32; o; o >>= 1) errsum += __shfl_down(errsum, o);
    if (lane == 0) red[wid] = errsum;
    __syncthreads();
    if (tid == 0) {
      float tot = 0.f;
#pragma unroll
      for (int w = 0; w < 16; ++w) tot += red[w];
      s_stop = (tot * UNSCALE < THRESH) ? 1 : 0;
    }
    __syncthreads();
    if (s_stop) break;
  }

  // cost_b = sum pi * Cm over the support (row-wise listing covers it once)
  float cs = 0.f;
  for (int n = tid; n < NN; n += 1024) {
    int cnt = 8 + min(r_cnt[(size_t)b*NN + n], CAP - 8);
    const int2* p = r_pk + ((size_t)b*NN + n) * CAP;
    float u = U[n];
    for (int e = 0; e < cnt; ++e) {
      int2 pk = p[e];
      float v2 = __int_as_float(pk.y);
      cs += FEXP2(u + V[pk.x] - v2) * v2;     // * (EPS*ln2) factored out below
    }
  }
#pragma unroll
  for (int o = 32; o; o >>= 1) cs += __shfl_down(cs, o);
  __syncthreads();
  if (lane == 0) red[wid] = cs;
  __syncthreads();
  if (tid == 0) {
    float tot = 0.f;
#pragma unroll
    for (int w = 0; w < 16; ++w) tot += red[w];
    cost[b] = tot * UNSCALE;
  }
}

__global__ void k_final(const float* __restrict__ cost, float* __restrict__ out) {
  if (threadIdx.x == 0 && blockIdx.x == 0) {
    float s = 0.f;
#pragma unroll
    for (int b = 0; b < NB; ++b) s += cost[b];
    out[0] = s * (1.0f / NB);
  }
}

// ---------------------------------------------------------------------------
extern "C" void kernel_launch(void* const* d_in, const int* in_sizes, int n_in,
                              void* d_out, int out_size, void* d_ws, size_t ws_size,
                              hipStream_t stream) {
  const float* mu = (const float*)d_in[0];
  const float* nu = (const float*)d_in[1];
  const float* C  = (const float*)d_in[2];
  float* out = (float*)d_out;

  char* ws = (char*)d_ws;
  size_t off = 0;
  auto alloc = [&](size_t bytes) {
    void* p = ws + off;
    off += (bytes + 255) & ~(size_t)255;
    return p;
  };
  float* norms  = (float*)alloc(sizeof(float) * NB * NN);
  int*   rowsel = (int*)  alloc(sizeof(int)   * NB * NN * KK);
  int*   colsel = (int*)  alloc(sizeof(int)   * NB * NM * KK);
  int*   r_cnt  = (int*)  alloc(sizeof(int)   * NB * NN);
  int*   c_cnt  = (int*)  alloc(sizeof(int)   * NB * NM);
  int2*  r_pk   = (int2*) alloc(sizeof(int2)  * NB * NN * CAP);
  int2*  c_pk   = (int2*) alloc(sizeof(int2)  * NB * NM * CAP);
  float* cost   = (float*)alloc(sizeof(float) * NB);
  (void)ws_size; (void)in_sizes; (void)n_in; (void)out_size;

  hipMemsetAsync(r_cnt, 0, sizeof(int) * NB * NN, stream);
  hipMemsetAsync(c_cnt, 0, sizeof(int) * NB * NM, stream);

  hipLaunchKernelGGL(k_rowprep, dim3(NB * NN), dim3(256), 0, stream, C, norms, rowsel);
  hipLaunchKernelGGL(k_coltop, dim3((NM + COLS - 1) / COLS, NB), dim3(512), 0, stream,
                     C, norms, colsel);
  int nthreads = NB * NN * KK;
  hipLaunchKernelGGL(k_fillbase, dim3((nthreads + 255) / 256), dim3(256), 0, stream,
                     C, norms, rowsel, colsel, r_pk, c_pk);
  hipLaunchKernelGGL(k_fillextra, dim3((nthreads + 255) / 256), dim3(256), 0, stream,
                     C, norms, rowsel, colsel, r_cnt, c_cnt, r_pk, c_pk);
  hipLaunchKernelGGL(k_sinkhorn, dim3(NB), dim3(1024), 0, stream,
                     mu, nu, r_pk, r_cnt, c_pk, c_cnt, cost);
  hipLaunchKernelGGL(k_final, dim3(1), dim3(64), 0, stream, cost, out);
}